// Round 1
// baseline (399.993 us; speedup 1.0000x reference)
//
#include <hip/hip_runtime.h>
#include <math.h>

#define EPSF 1e-6f

// Block-level sum reduction (256 threads = 4 waves of 64). Result valid on thread 0.
__device__ __forceinline__ float block_reduce_sum(float v) {
    #pragma unroll
    for (int off = 32; off > 0; off >>= 1)
        v += __shfl_down(v, off, 64);
    __shared__ float smem[4];
    int lane = threadIdx.x & 63;
    int wid  = threadIdx.x >> 6;
    if (lane == 0) smem[wid] = v;
    __syncthreads();
    float s = 0.0f;
    if (threadIdx.x == 0) {
        #pragma unroll
        for (int w = 0; w < 4; w++) s += smem[w];
    }
    return s;
}

__global__ void __launch_bounds__(256)
ciou_loss_kernel(const float* __restrict__ pred,
                 const float* __restrict__ target,
                 const float* __restrict__ weight,
                 float* __restrict__ partial,
                 int N)
{
    int idx = blockIdx.x * 256 + threadIdx.x;
    float contrib = 0.0f;
    if (idx < N) {
        const float* p = pred   + (size_t)idx * 5;
        const float* t = target + (size_t)idx * 5;
        float px = p[0], py = p[1], pw = p[2], ph = p[3], pa = p[4];
        float tx = t[0], ty = t[1], tw = t[2], th = t[3], ta = t[4];

        // ---- box2corners (order: (+,+), (-,+), (-,-), (+,-) half-extents) ----
        const float sgx[4] = { 0.5f, -0.5f, -0.5f,  0.5f };
        const float sgy[4] = { 0.5f,  0.5f, -0.5f, -0.5f };
        float c1x[4], c1y[4], c2x[4], c2y[4];
        float ca, sa, cb, sb;
        __sincosf(pa, &sa, &ca);
        __sincosf(ta, &sb, &cb);
        #pragma unroll
        for (int i = 0; i < 4; i++) {
            float x4 = sgx[i] * pw, y4 = sgy[i] * ph;
            c1x[i] = x4 * ca - y4 * sa + px;
            c1y[i] = x4 * sa + y4 * ca + py;
        }
        #pragma unroll
        for (int i = 0; i < 4; i++) {
            float x4 = sgx[i] * tw, y4 = sgy[i] * th;
            c2x[i] = x4 * cb - y4 * sb + tx;
            c2y[i] = x4 * sb + y4 * cb + ty;
        }

        // ---- collect valid candidate vertices in the reference's slot order ----
        float vx[24], vy[24];
        int nv = 0;

        // slots 0-3: c1 corners inside c2
        {
            float ax = c2x[0], ay = c2y[0];
            float abx = c2x[1] - ax, aby = c2y[1] - ay;
            float adx = c2x[3] - ax, ady = c2y[3] - ay;
            float dab = fmaxf(abx * abx + aby * aby, EPSF);
            float dad = fmaxf(adx * adx + ady * ady, EPSF);
            #pragma unroll
            for (int i = 0; i < 4; i++) {
                float amx = c1x[i] - ax, amy = c1y[i] - ay;
                float pab = (amx * abx + amy * aby) / dab;
                float pad = (amx * adx + amy * ady) / dad;
                if (pab > -1e-6f && pab < 1.0f + 1e-6f &&
                    pad > -1e-6f && pad < 1.0f + 1e-6f) {
                    vx[nv] = c1x[i]; vy[nv] = c1y[i]; nv++;
                }
            }
        }
        // slots 4-7: c2 corners inside c1
        {
            float ax = c1x[0], ay = c1y[0];
            float abx = c1x[1] - ax, aby = c1y[1] - ay;
            float adx = c1x[3] - ax, ady = c1y[3] - ay;
            float dab = fmaxf(abx * abx + aby * aby, EPSF);
            float dad = fmaxf(adx * adx + ady * ady, EPSF);
            #pragma unroll
            for (int i = 0; i < 4; i++) {
                float amx = c2x[i] - ax, amy = c2y[i] - ay;
                float pab = (amx * abx + amy * aby) / dab;
                float pad = (amx * adx + amy * ady) / dad;
                if (pab > -1e-6f && pab < 1.0f + 1e-6f &&
                    pad > -1e-6f && pad < 1.0f + 1e-6f) {
                    vx[nv] = c2x[i]; vy[nv] = c2y[i]; nv++;
                }
            }
        }
        // slots 8-23: edge-pair intersections (i = c1 edge outer, j = c2 edge inner)
        #pragma unroll
        for (int i = 0; i < 4; i++) {
            float p1x = c1x[i], p1y = c1y[i];
            float d1x = c1x[(i + 1) & 3] - p1x, d1y = c1y[(i + 1) & 3] - p1y;
            #pragma unroll
            for (int j = 0; j < 4; j++) {
                float p2x = c2x[j], p2y = c2y[j];
                float d2x = c2x[(j + 1) & 3] - p2x, d2y = c2y[(j + 1) & 3] - p2y;
                float den = d1x * d2y - d1y * d2x;
                if (fabsf(den) > 1e-12f) {
                    float dpx = p2x - p1x, dpy = p2y - p1y;
                    float tt = (dpx * d2y - dpy * d2x) / den;
                    float uu = (dpx * d1y - dpy * d1x) / den;
                    if (tt > 0.0f && tt < 1.0f && uu > 0.0f && uu < 1.0f) {
                        vx[nv] = p1x + tt * d1x;
                        vy[nv] = p1y + tt * d1y;
                        nv++;
                    }
                }
            }
        }

        // ---- centroid, recenter, angles ----
        float sx = 0.0f, sy = 0.0f;
        for (int k = 0; k < nv; k++) { sx += vx[k]; sy += vy[k]; }
        float invn = (nv > 0) ? (1.0f / (float)nv) : 0.0f;
        float mx = sx * invn, my = sy * invn;
        float ang[24];
        for (int k = 0; k < nv; k++) {
            vx[k] -= mx; vy[k] -= my;
            ang[k] = atan2f(vy[k], vx[k]);
        }

        // ---- stable insertion sort by angle (matches jnp.argsort stability) ----
        for (int k = 1; k < nv; k++) {
            float a = ang[k], x = vx[k], y = vy[k];
            int j = k - 1;
            while (j >= 0 && ang[j] > a) {
                ang[j + 1] = ang[j]; vx[j + 1] = vx[j]; vy[j + 1] = vy[j];
                j--;
            }
            ang[j + 1] = a; vx[j + 1] = x; vy[j + 1] = y;
        }

        // ---- shoelace (closed polygon) ----
        float area2 = 0.0f;
        for (int k = 0; k < nv; k++) {
            int kn = (k + 1 == nv) ? 0 : k + 1;
            area2 += vx[k] * vy[kn] - vy[k] * vx[kn];
        }
        float inter = 0.5f * fabsf(area2);

        // ---- CIoU loss ----
        float a1 = pw * ph, a2 = tw * th;
        float iou = inter / (a1 + a2 - inter);
        iou = fmaxf(iou, EPSF);  // jnp.clip(x, EPS) — min clip only
        float dx0 = px - tx, dy0 = py - ty;
        float cd = dx0 * dx0 + dy0 * dy0;
        float da = atanf(tw / (th + EPSF)) - atanf(pw / (ph + EPSF));
        const float c4pi2 = 4.0f / (3.14159265358979323846f * 3.14159265358979323846f);
        float aspect = c4pi2 * da * da;
        float vterm = aspect / (1.0f - iou + aspect);
        float alpha = vterm / (1.0f - iou + vterm);
        float loss = 1.0f - iou + cd / (pw * pw + ph * ph + EPSF) + alpha * vterm;
        contrib = loss * weight[idx];
    }

    float s = block_reduce_sum(contrib);
    if (threadIdx.x == 0) partial[blockIdx.x] = s;
}

__global__ void __launch_bounds__(256)
reduce_final_kernel(const float* __restrict__ partial, int nparts, float invN,
                    float* __restrict__ out)
{
    float s = 0.0f;
    for (int i = threadIdx.x; i < nparts; i += 256) s += partial[i];
    s = block_reduce_sum(s);
    if (threadIdx.x == 0) out[0] = s * invN;
}

extern "C" void kernel_launch(void* const* d_in, const int* in_sizes, int n_in,
                              void* d_out, int out_size, void* d_ws, size_t ws_size,
                              hipStream_t stream) {
    const float* pred   = (const float*)d_in[0];
    const float* target = (const float*)d_in[1];
    const float* weight = (const float*)d_in[2];
    int N = in_sizes[2];              // weight has N elements
    float* partial = (float*)d_ws;    // one float per block, blocks write before read

    int blocks = (N + 255) / 256;
    ciou_loss_kernel<<<blocks, 256, 0, stream>>>(pred, target, weight, partial, N);
    reduce_final_kernel<<<1, 256, 0, stream>>>(partial, blocks, 1.0f / (float)N,
                                               (float*)d_out);
}

// Round 2
// 110.613 us; speedup vs baseline: 3.6161x; 3.6161x over previous
//
#include <hip/hip_runtime.h>
#include <math.h>

#define EPSF 1e-6f

// Block-level sum reduction (256 threads = 4 waves of 64). Result valid on thread 0.
__device__ __forceinline__ float block_reduce_sum(float v) {
    #pragma unroll
    for (int off = 32; off > 0; off >>= 1)
        v += __shfl_down(v, off, 64);
    __shared__ float smem[4];
    int lane = threadIdx.x & 63;
    int wid  = threadIdx.x >> 6;
    if (lane == 0) smem[wid] = v;
    __syncthreads();
    float s = 0.0f;
    if (threadIdx.x == 0) {
        #pragma unroll
        for (int w = 0; w < 4; w++) s += smem[w];
    }
    return s;
}

// Intersection area of two convex quads via Sutherland-Hodgman clipping.
// Polygon buffers live in LDS, lane-major (poly[buf][vert][tid]) so consecutive
// lanes hit consecutive banks (8B/lane contiguous -> conflict-free pattern).
__global__ void __launch_bounds__(256)
ciou_loss_kernel(const float* __restrict__ pred,
                 const float* __restrict__ target,
                 const float* __restrict__ weight,
                 float* __restrict__ partial,
                 int N)
{
    __shared__ float2 poly[2][8][256];   // 32 KB

    int tid = threadIdx.x;
    int idx = blockIdx.x * 256 + tid;
    float contrib = 0.0f;
    if (idx < N) {
        const float* p = pred   + (size_t)idx * 5;
        const float* t = target + (size_t)idx * 5;
        float px = p[0], py = p[1], pw = p[2], ph = p[3], pa = p[4];
        float tx = t[0], ty = t[1], tw = t[2], th = t[3], ta = t[4];

        // ---- box2corners: CCW order (+,+), (-,+), (-,-), (+,-) ----
        const float sgx[4] = { 0.5f, -0.5f, -0.5f,  0.5f };
        const float sgy[4] = { 0.5f,  0.5f, -0.5f, -0.5f };
        float c2x[4], c2y[4];
        float ca, sa, cb, sb;
        __sincosf(pa, &sa, &ca);
        __sincosf(ta, &sb, &cb);
        // subject polygon = c1 (pred corners) -> LDS buffer 0
        #pragma unroll
        for (int i = 0; i < 4; i++) {
            float x4 = sgx[i] * pw, y4 = sgy[i] * ph;
            poly[0][i][tid] = make_float2(x4 * ca - y4 * sa + px,
                                          x4 * sa + y4 * ca + py);
        }
        // clip polygon = c2 (target corners), stays in registers
        #pragma unroll
        for (int i = 0; i < 4; i++) {
            float x4 = sgx[i] * tw, y4 = sgy[i] * th;
            c2x[i] = x4 * cb - y4 * sb + tx;
            c2y[i] = x4 * sb + y4 * cb + ty;
        }

        // ---- Sutherland-Hodgman: clip subject against each CCW edge of c2 ----
        int cur = 0, n = 4;
        #pragma unroll
        for (int e = 0; e < 4; e++) {
            float ax = c2x[e], ay = c2y[e];
            float ex = c2x[(e + 1) & 3] - ax;
            float ey = c2y[(e + 1) & 3] - ay;
            int m = 0;
            if (n > 0) {
                float2 first = poly[cur][0][tid];
                float2 C = first;
                float dc = ex * (C.y - ay) - ey * (C.x - ax);   // >=0 == inside (left of edge)
                for (int k = 0; k < n; k++) {
                    float2 D;
                    if (k + 1 == n) D = first;
                    else            D = poly[cur][k + 1][tid];
                    float dd = ex * (D.y - ay) - ey * (D.x - ax);
                    bool cin = (dc >= 0.0f), din = (dd >= 0.0f);
                    if (cin && m < 8) { poly[cur ^ 1][m][tid] = C; m++; }
                    if (cin != din && m < 8) {
                        float tt = dc / (dc - dd);              // denom strictly nonzero when signs differ
                        poly[cur ^ 1][m][tid] =
                            make_float2(C.x + tt * (D.x - C.x), C.y + tt * (D.y - C.y));
                        m++;
                    }
                    C = D; dc = dd;
                }
            }
            cur ^= 1;
            n = m;
        }

        // ---- shoelace on the ordered (CCW) intersection polygon ----
        float area2 = 0.0f;
        if (n >= 3) {
            float2 first = poly[cur][0][tid];
            float2 prev = first;
            for (int k = 1; k < n; k++) {
                float2 v = poly[cur][k][tid];
                area2 += prev.x * v.y - prev.y * v.x;
                prev = v;
            }
            area2 += prev.x * first.y - prev.y * first.x;
        }
        float inter = 0.5f * fabsf(area2);

        // ---- CIoU loss ----
        float a1 = pw * ph, a2 = tw * th;
        float iou = inter / (a1 + a2 - inter);
        iou = fmaxf(iou, EPSF);  // jnp.clip(x, EPS) — min clip only
        float dx0 = px - tx, dy0 = py - ty;
        float cd = dx0 * dx0 + dy0 * dy0;
        float da = atanf(tw / (th + EPSF)) - atanf(pw / (ph + EPSF));
        const float c4pi2 = 4.0f / (3.14159265358979323846f * 3.14159265358979323846f);
        float aspect = c4pi2 * da * da;
        float vterm = aspect / (1.0f - iou + aspect);
        float alpha = vterm / (1.0f - iou + vterm);
        float loss = 1.0f - iou + cd / (pw * pw + ph * ph + EPSF) + alpha * vterm;
        contrib = loss * weight[idx];
    }

    float s = block_reduce_sum(contrib);
    if (threadIdx.x == 0) partial[blockIdx.x] = s;
}

__global__ void __launch_bounds__(256)
reduce_final_kernel(const float* __restrict__ partial, int nparts, float invN,
                    float* __restrict__ out)
{
    float s = 0.0f;
    for (int i = threadIdx.x; i < nparts; i += 256) s += partial[i];
    s = block_reduce_sum(s);
    if (threadIdx.x == 0) out[0] = s * invN;
}

extern "C" void kernel_launch(void* const* d_in, const int* in_sizes, int n_in,
                              void* d_out, int out_size, void* d_ws, size_t ws_size,
                              hipStream_t stream) {
    const float* pred   = (const float*)d_in[0];
    const float* target = (const float*)d_in[1];
    const float* weight = (const float*)d_in[2];
    int N = in_sizes[2];              // weight has N elements
    float* partial = (float*)d_ws;    // one float per block, each block writes its own slot

    int blocks = (N + 255) / 256;
    ciou_loss_kernel<<<blocks, 256, 0, stream>>>(pred, target, weight, partial, N);
    reduce_final_kernel<<<1, 256, 0, stream>>>(partial, blocks, 1.0f / (float)N,
                                               (float*)d_out);
}

// Round 3
// 102.836 us; speedup vs baseline: 3.8896x; 1.0756x over previous
//
#include <hip/hip_runtime.h>
#include <math.h>

#define EPSF 1e-6f

// Block-level sum reduction (256 threads = 4 waves of 64). Result valid on thread 0.
__device__ __forceinline__ float block_reduce_sum(float v) {
    #pragma unroll
    for (int off = 32; off > 0; off >>= 1)
        v += __shfl_down(v, off, 64);
    __shared__ float smem[4];
    int lane = threadIdx.x & 63;
    int wid  = threadIdx.x >> 6;
    if (lane == 0) smem[wid] = v;
    __syncthreads();
    float s = 0.0f;
    if (threadIdx.x == 0) {
        #pragma unroll
        for (int w = 0; w < 4; w++) s += smem[w];
    }
    return s;
}

// Intersection area of two convex quads, branchless:
// 2*Area(P ∩ Q) = sum over boundary segments of cross(start, end).
// Boundary segments = each P-edge Liang-Barsky-clipped to Q's 4 half-planes,
// plus each Q-edge clipped to P. Order-independent sum -> no polygon build,
// no sort, no LDS, no divergent loops.
__global__ void __launch_bounds__(256)
ciou_loss_kernel(const float* __restrict__ pred,
                 const float* __restrict__ target,
                 const float* __restrict__ weight,
                 float* __restrict__ partial,
                 int N)
{
    int tid = threadIdx.x;
    int idx = blockIdx.x * 256 + tid;
    float contrib = 0.0f;
    if (idx < N) {
        const float* p = pred   + (size_t)idx * 5;
        const float* t = target + (size_t)idx * 5;
        float px = p[0], py = p[1], pw = p[2], ph = p[3], pa = p[4];
        float tx = t[0], ty = t[1], tw = t[2], th = t[3], ta = t[4];

        // Recenter at the midpoint of the two centers: keeps cross-product
        // operands O(box size) instead of O(1024) -> fp32 cancellation ~1e-4.
        float cx0 = 0.5f * (px + tx), cy0 = 0.5f * (py + ty);

        // ---- corners (CCW): (+,+), (-,+), (-,-), (+,-) half-extents ----
        const float sgx[4] = { 0.5f, -0.5f, -0.5f,  0.5f };
        const float sgy[4] = { 0.5f,  0.5f, -0.5f, -0.5f };
        float Pxv[4], Pyv[4], Qxv[4], Qyv[4];
        float ca, sa, cb, sb;
        __sincosf(pa, &sa, &ca);
        __sincosf(ta, &sb, &cb);
        #pragma unroll
        for (int i = 0; i < 4; i++) {
            float x4 = sgx[i] * pw, y4 = sgy[i] * ph;
            Pxv[i] = x4 * ca - y4 * sa + (px - cx0);
            Pyv[i] = x4 * sa + y4 * ca + (py - cy0);
            float u4 = sgx[i] * tw, v4 = sgy[i] * th;
            Qxv[i] = u4 * cb - v4 * sb + (tx - cx0);
            Qyv[i] = u4 * sb + v4 * cb + (ty - cy0);
        }

        // ---- edge vectors ----
        float Pex[4], Pey[4], Qex[4], Qey[4];
        #pragma unroll
        for (int i = 0; i < 4; i++) {
            Pex[i] = Pxv[(i + 1) & 3] - Pxv[i];
            Pey[i] = Pyv[(i + 1) & 3] - Pyv[i];
            Qex[i] = Qxv[(i + 1) & 3] - Qxv[i];
            Qey[i] = Qyv[(i + 1) & 3] - Qyv[i];
        }

        // ---- signed-distance matrices (inside = left of CCW edge, f >= 0) ----
        // dPQ[i][j] = f_{Q-edge j}(P vertex i);  dQP[j][i] = f_{P-edge i}(Q vertex j)
        float dPQ[4][4], dQP[4][4];
        #pragma unroll
        for (int i = 0; i < 4; i++) {
            #pragma unroll
            for (int j = 0; j < 4; j++) {
                dPQ[i][j] = Qex[j] * (Pyv[i] - Qyv[j]) - Qey[j] * (Pxv[i] - Qxv[j]);
                dQP[i][j] = Pex[j] * (Qyv[i] - Pyv[j]) - Pey[j] * (Qxv[i] - Pxv[j]);
            }
        }

        float area2 = 0.0f;

        // ---- P edges clipped against Q's half-planes ----
        #pragma unroll
        for (int i = 0; i < 4; i++) {
            int ip = (i + 1) & 3;
            float Cx = Pxv[i], Cy = Pyv[i];
            float ex = Pex[i], ey = Pey[i];
            float t0 = 0.0f, t1 = 1.0f;
            #pragma unroll
            for (int j = 0; j < 4; j++) {
                float dc = dPQ[i][j], dd = dPQ[ip][j];
                float denom = dc - dd;                 // = -(dd-dc)
                bool  par   = fabsf(denom) < 1e-12f;
                float ds    = par ? 1.0f : denom;
                float tt    = dc * __builtin_amdgcn_rcpf(ds);
                bool  enter = denom < 0.0f;            // f increasing along edge
                t0 = (!par &&  enter) ? fmaxf(t0, tt) : t0;
                t1 = (!par && !enter) ? fminf(t1, tt) : t1;
                t1 = (par && dc < 0.0f) ? -1.0f : t1;  // parallel & fully outside
            }
            float t1c = fmaxf(t1, t0);                 // empty clip -> A==B -> 0
            float Ax = Cx + t0  * ex, Ay = Cy + t0  * ey;
            float Bx = Cx + t1c * ex, By = Cy + t1c * ey;
            area2 += Ax * By - Ay * Bx;
        }

        // ---- Q edges clipped against P's half-planes ----
        #pragma unroll
        for (int i = 0; i < 4; i++) {
            int ip = (i + 1) & 3;
            float Cx = Qxv[i], Cy = Qyv[i];
            float ex = Qex[i], ey = Qey[i];
            float t0 = 0.0f, t1 = 1.0f;
            #pragma unroll
            for (int j = 0; j < 4; j++) {
                float dc = dQP[i][j], dd = dQP[ip][j];
                float denom = dc - dd;
                bool  par   = fabsf(denom) < 1e-12f;
                float ds    = par ? 1.0f : denom;
                float tt    = dc * __builtin_amdgcn_rcpf(ds);
                bool  enter = denom < 0.0f;
                t0 = (!par &&  enter) ? fmaxf(t0, tt) : t0;
                t1 = (!par && !enter) ? fminf(t1, tt) : t1;
                t1 = (par && dc < 0.0f) ? -1.0f : t1;
            }
            float t1c = fmaxf(t1, t0);
            float Ax = Cx + t0  * ex, Ay = Cy + t0  * ey;
            float Bx = Cx + t1c * ex, By = Cy + t1c * ey;
            area2 += Ax * By - Ay * Bx;
        }

        float inter = 0.5f * fabsf(area2);

        // ---- CIoU loss (absolute-coordinate quantities) ----
        float a1 = pw * ph, a2 = tw * th;
        float iou = inter / (a1 + a2 - inter);
        iou = fmaxf(iou, EPSF);  // jnp.clip(x, EPS) — min clip only
        float dx0 = px - tx, dy0 = py - ty;
        float cd = dx0 * dx0 + dy0 * dy0;
        float da = atanf(tw / (th + EPSF)) - atanf(pw / (ph + EPSF));
        const float c4pi2 = 4.0f / (3.14159265358979323846f * 3.14159265358979323846f);
        float aspect = c4pi2 * da * da;
        float vterm = aspect / (1.0f - iou + aspect);
        float alpha = vterm / (1.0f - iou + vterm);
        float loss = 1.0f - iou + cd / (pw * pw + ph * ph + EPSF) + alpha * vterm;
        contrib = loss * weight[idx];
    }

    float s = block_reduce_sum(contrib);
    if (threadIdx.x == 0) partial[blockIdx.x] = s;
}

__global__ void __launch_bounds__(256)
reduce_final_kernel(const float* __restrict__ partial, int nparts, float invN,
                    float* __restrict__ out)
{
    float s = 0.0f;
    for (int i = threadIdx.x; i < nparts; i += 256) s += partial[i];
    s = block_reduce_sum(s);
    if (threadIdx.x == 0) out[0] = s * invN;
}

extern "C" void kernel_launch(void* const* d_in, const int* in_sizes, int n_in,
                              void* d_out, int out_size, void* d_ws, size_t ws_size,
                              hipStream_t stream) {
    const float* pred   = (const float*)d_in[0];
    const float* target = (const float*)d_in[1];
    const float* weight = (const float*)d_in[2];
    int N = in_sizes[2];              // weight has N elements
    float* partial = (float*)d_ws;    // one float per block, each block writes its own slot

    int blocks = (N + 255) / 256;
    ciou_loss_kernel<<<blocks, 256, 0, stream>>>(pred, target, weight, partial, N);
    reduce_final_kernel<<<1, 256, 0, stream>>>(partial, blocks, 1.0f / (float)N,
                                               (float*)d_out);
}

// Round 5
// 96.283 us; speedup vs baseline: 4.1543x; 1.0681x over previous
//
#include <hip/hip_runtime.h>
#include <math.h>

#define EPSF 1e-6f

// Wave(64)-then-LDS block reduction, templated on wave count. Valid on thread 0.
template <int NWAVES>
__device__ __forceinline__ float block_reduce_sum(float v) {
    #pragma unroll
    for (int off = 32; off > 0; off >>= 1)
        v += __shfl_down(v, off, 64);
    __shared__ float smem[NWAVES];
    int lane = threadIdx.x & 63;
    int wid  = threadIdx.x >> 6;
    if (lane == 0) smem[wid] = v;
    __syncthreads();
    float s = 0.0f;
    if (threadIdx.x == 0) {
        #pragma unroll
        for (int w = 0; w < NWAVES; w++) s += smem[w];
    }
    return s;
}

// atan via degree-11 minimax on [0,1] + reciprocal fold; |err| ~1e-6.
__device__ __forceinline__ float fast_atan(float x) {
    const float a1  =  0.99997726f, a3 = -0.33262347f, a5  =  0.19354346f,
                a7  = -0.11643287f, a9 =  0.05265332f, a11 = -0.01172120f;
    float ax  = fabsf(x);
    bool  big = ax > 1.0f;
    float z   = big ? __builtin_amdgcn_rcpf(ax) : ax;   // z in [0,1]
    float z2  = z * z;
    float p   = fmaf(z2, a11, a9);
    p = fmaf(z2, p, a7);
    p = fmaf(z2, p, a5);
    p = fmaf(z2, p, a3);
    p = fmaf(z2, p, a1);
    float r = z * p;
    r = big ? (1.57079632679f - r) : r;
    return copysignf(r, x);
}

// 2*Area(P ∩ Q) = Σ over boundary segments cross(start,end)
//              = Σ_edges (t1 - t0) * cross(v_i, v_{i+1})   [Liang-Barsky t-range]
// Fully branchless, register-only.
// Signed distance of point X from CCW edge (v_j -> v_{j+1}) with e = v_{j+1}-v_j,
// c_j = cross(v_j, v_{j+1}):  d = e.x*X.y - e.y*X.x + c_j   (>= 0 inside).
// [R4 bug was "- c_j"; unit-square check: edge (1,0)->(1,1) gives d = 1 - X.x. ✓]
__global__ void __launch_bounds__(256)
ciou_loss_kernel(const float* __restrict__ pred,
                 const float* __restrict__ target,
                 const float* __restrict__ weight,
                 float* __restrict__ partial,
                 int N)
{
    int tid = threadIdx.x;
    int idx = blockIdx.x * 256 + tid;
    float contrib = 0.0f;
    if (idx < N) {
        const float* p = pred   + (size_t)idx * 5;
        const float* t = target + (size_t)idx * 5;
        float px = p[0], py = p[1], pw = p[2], ph = p[3], pa = p[4];
        float tx = t[0], ty = t[1], tw = t[2], th = t[3], ta = t[4];
        float wgt = weight[idx];

        // Recenter at midpoint of centers: operands O(box size), not O(1024).
        float cx0 = 0.5f * (px + tx), cy0 = 0.5f * (py + ty);

        // ---- corners (CCW): (+,+), (-,+), (-,-), (+,-) ----
        const float sgx[4] = { 0.5f, -0.5f, -0.5f,  0.5f };
        const float sgy[4] = { 0.5f,  0.5f, -0.5f, -0.5f };
        float Pxv[4], Pyv[4], Qxv[4], Qyv[4];
        float ca, sa, cb, sb;
        __sincosf(pa, &sa, &ca);
        __sincosf(ta, &sb, &cb);
        #pragma unroll
        for (int i = 0; i < 4; i++) {
            float x4 = sgx[i] * pw, y4 = sgy[i] * ph;
            Pxv[i] = x4 * ca - y4 * sa + (px - cx0);
            Pyv[i] = x4 * sa + y4 * ca + (py - cy0);
            float u4 = sgx[i] * tw, v4 = sgy[i] * th;
            Qxv[i] = u4 * cb - v4 * sb + (tx - cx0);
            Qyv[i] = u4 * sb + v4 * cb + (ty - cy0);
        }

        // ---- edge vectors + per-edge cross constants c[j] = cross(v_j, v_{j+1}) ----
        float Pex[4], Pey[4], Qex[4], Qey[4], cP[4], cQ[4];
        #pragma unroll
        for (int i = 0; i < 4; i++) {
            int ip = (i + 1) & 3;
            Pex[i] = Pxv[ip] - Pxv[i];
            Pey[i] = Pyv[ip] - Pyv[i];
            Qex[i] = Qxv[ip] - Qxv[i];
            Qey[i] = Qyv[ip] - Qyv[i];
            cP[i]  = Pxv[i] * Pyv[ip] - Pyv[i] * Pxv[ip];
            cQ[i]  = Qxv[i] * Qyv[ip] - Qyv[i] * Qxv[ip];
        }

        float area2 = 0.0f;

        // ===== pass 1: P edges clipped against Q's half-planes =====
        {
            float d[4][4];
            #pragma unroll
            for (int i = 0; i < 4; i++)
                #pragma unroll
                for (int j = 0; j < 4; j++)
                    d[i][j] = fmaf(Qex[j], Pyv[i], fmaf(-Qey[j], Pxv[i], cQ[j]));

            #pragma unroll
            for (int i = 0; i < 4; i++) {
                int ip = (i + 1) & 3;
                float t0 = 0.0f, t1 = 1.0f;
                #pragma unroll
                for (int j = 0; j < 4; j++) {
                    float dc = d[i][j], dd = d[ip][j];
                    float denom = dc - dd;
                    float ds = copysignf(fmaxf(fabsf(denom), 1e-12f), denom);
                    float tt = dc * __builtin_amdgcn_rcpf(ds);
                    bool  enter = denom < 0.0f;      // f increases along edge
                    t0 = fmaxf(t0, enter ? tt : 0.0f);
                    t1 = fminf(t1, enter ? 1.0f : tt);
                }
                area2 = fmaf(fmaxf(t1, t0) - t0, cP[i], area2);
            }
        }

        // ===== pass 2: Q edges clipped against P's half-planes =====
        {
            float d[4][4];
            #pragma unroll
            for (int i = 0; i < 4; i++)
                #pragma unroll
                for (int j = 0; j < 4; j++)
                    d[i][j] = fmaf(Pex[j], Qyv[i], fmaf(-Pey[j], Qxv[i], cP[j]));

            #pragma unroll
            for (int i = 0; i < 4; i++) {
                int ip = (i + 1) & 3;
                float t0 = 0.0f, t1 = 1.0f;
                #pragma unroll
                for (int j = 0; j < 4; j++) {
                    float dc = d[i][j], dd = d[ip][j];
                    float denom = dc - dd;
                    float ds = copysignf(fmaxf(fabsf(denom), 1e-12f), denom);
                    float tt = dc * __builtin_amdgcn_rcpf(ds);
                    bool  enter = denom < 0.0f;
                    t0 = fmaxf(t0, enter ? tt : 0.0f);
                    t1 = fminf(t1, enter ? 1.0f : tt);
                }
                area2 = fmaf(fmaxf(t1, t0) - t0, cQ[i], area2);
            }
        }

        float inter = 0.5f * fabsf(area2);

        // ---- CIoU loss ----
        float a1 = pw * ph, a2 = tw * th;
        float iou = inter / (a1 + a2 - inter);
        iou = fmaxf(iou, EPSF);  // jnp.clip(x, EPS) — min clip only
        float dx0 = px - tx, dy0 = py - ty;
        float cd = dx0 * dx0 + dy0 * dy0;
        // atan(u)-atan(v) = atan((u-v)/(1+uv)) for u,v>0
        float u  = tw * __builtin_amdgcn_rcpf(th + EPSF);
        float v  = pw * __builtin_amdgcn_rcpf(ph + EPSF);
        float da = fast_atan((u - v) * __builtin_amdgcn_rcpf(fmaf(u, v, 1.0f)));
        const float c4pi2 = 4.0f / (3.14159265358979323846f * 3.14159265358979323846f);
        float aspect = c4pi2 * da * da;
        float vterm = aspect / (1.0f - iou + aspect);
        float alpha = vterm / (1.0f - iou + vterm);
        float loss = 1.0f - iou + cd / (pw * pw + ph * ph + EPSF) + alpha * vterm;
        contrib = loss * wgt;
    }

    float s = block_reduce_sum<4>(contrib);
    if (threadIdx.x == 0) partial[blockIdx.x] = s;
}

__global__ void __launch_bounds__(1024)
reduce_final_kernel(const float* __restrict__ partial, int nparts, float invN,
                    float* __restrict__ out)
{
    float s = 0.0f;
    for (int i = threadIdx.x; i < nparts; i += 1024) s += partial[i];
    s = block_reduce_sum<16>(s);
    if (threadIdx.x == 0) out[0] = s * invN;
}

extern "C" void kernel_launch(void* const* d_in, const int* in_sizes, int n_in,
                              void* d_out, int out_size, void* d_ws, size_t ws_size,
                              hipStream_t stream) {
    const float* pred   = (const float*)d_in[0];
    const float* target = (const float*)d_in[1];
    const float* weight = (const float*)d_in[2];
    int N = in_sizes[2];              // weight has N elements
    float* partial = (float*)d_ws;    // one float per block, each block writes its own slot

    int blocks = (N + 255) / 256;
    ciou_loss_kernel<<<blocks, 256, 0, stream>>>(pred, target, weight, partial, N);
    reduce_final_kernel<<<1, 1024, 0, stream>>>(partial, blocks, 1.0f / (float)N,
                                                (float*)d_out);
}

// Round 6
// 92.046 us; speedup vs baseline: 4.3456x; 1.0460x over previous
//
#include <hip/hip_runtime.h>
#include <math.h>

#define EPSF 1e-6f

// Wave(64)-then-LDS block reduction, templated on wave count. Valid on thread 0.
template <int NWAVES>
__device__ __forceinline__ float block_reduce_sum(float v) {
    #pragma unroll
    for (int off = 32; off > 0; off >>= 1)
        v += __shfl_down(v, off, 64);
    __shared__ float smem[NWAVES];
    int lane = threadIdx.x & 63;
    int wid  = threadIdx.x >> 6;
    if (lane == 0) smem[wid] = v;
    __syncthreads();
    float s = 0.0f;
    if (threadIdx.x == 0) {
        #pragma unroll
        for (int w = 0; w < NWAVES; w++) s += smem[w];
    }
    return s;
}

// atan via degree-11 minimax on [0,1] + reciprocal fold; |err| ~1e-6.
__device__ __forceinline__ float fast_atan(float x) {
    const float a1  =  0.99997726f, a3 = -0.33262347f, a5  =  0.19354346f,
                a7  = -0.11643287f, a9 =  0.05265332f, a11 = -0.01172120f;
    float ax  = fabsf(x);
    bool  big = ax > 1.0f;
    float z   = big ? __builtin_amdgcn_rcpf(ax) : ax;   // z in [0,1]
    float z2  = z * z;
    float p   = fmaf(z2, a11, a9);
    p = fmaf(z2, p, a7);
    p = fmaf(z2, p, a5);
    p = fmaf(z2, p, a3);
    p = fmaf(z2, p, a1);
    float r = z * p;
    r = big ? (1.57079632679f - r) : r;
    return copysignf(r, x);
}

// 2*Area(P ∩ Q) = Σ_edges (t1 - t0) * cross(v_i, v_{i+1})  [Liang-Barsky t-range
// per edge against the other quad's 4 half-planes]. Branchless, register-only.
//
// Signed distance of X from CCW edge (v_j -> v_{j+1}), e = v_{j+1}-v_j,
// c_j = cross(v_j, v_{j+1}):  d = e.x*X.y - e.y*X.x + c_j  (>= 0 inside).
//
// Fused-pass identity: denom1(i,j) = dPQ[i][j]-dPQ[i+1][j] = cross(Pe_i,Qe_j)
// and denom2(j,i) = -denom1 -> one rcp serves both passes (tt2 = dQP*(-r),
// enter2 = !enter1; exact-zero denom falls on the same safe side as the old
// +0.0 convention: outside -> empty range, inside -> no-op).
__global__ void __launch_bounds__(256)
ciou_loss_kernel(const float* __restrict__ pred,
                 const float* __restrict__ target,
                 const float* __restrict__ weight,
                 float* __restrict__ partial,
                 int N)
{
    int tid = threadIdx.x;
    int idx = blockIdx.x * 256 + tid;
    float contrib = 0.0f;
    if (idx < N) {
        const float* p = pred   + (size_t)idx * 5;
        const float* t = target + (size_t)idx * 5;
        float px = p[0], py = p[1], pw = p[2], ph = p[3], pa = p[4];
        float tx = t[0], ty = t[1], tw = t[2], th = t[3], ta = t[4];
        float wgt = weight[idx];

        // Recenter at midpoint of centers: operands O(box size), not O(1024).
        float cx0 = 0.5f * (px + tx), cy0 = 0.5f * (py + ty);

        // ---- corners (CCW): (+,+), (-,+), (-,-), (+,-) ----
        const float sgx[4] = { 0.5f, -0.5f, -0.5f,  0.5f };
        const float sgy[4] = { 0.5f,  0.5f, -0.5f, -0.5f };
        float Pxv[4], Pyv[4], Qxv[4], Qyv[4];
        float ca, sa, cb, sb;
        __sincosf(pa, &sa, &ca);
        __sincosf(ta, &sb, &cb);
        #pragma unroll
        for (int i = 0; i < 4; i++) {
            float x4 = sgx[i] * pw, y4 = sgy[i] * ph;
            Pxv[i] = x4 * ca - y4 * sa + (px - cx0);
            Pyv[i] = x4 * sa + y4 * ca + (py - cy0);
            float u4 = sgx[i] * tw, v4 = sgy[i] * th;
            Qxv[i] = u4 * cb - v4 * sb + (tx - cx0);
            Qyv[i] = u4 * sb + v4 * cb + (ty - cy0);
        }

        // ---- edge vectors + cross constants c[j] = cross(v_j, v_{j+1}) ----
        float Pex[4], Pey[4], Qex[4], Qey[4], cP[4], cQ[4];
        #pragma unroll
        for (int i = 0; i < 4; i++) {
            int ip = (i + 1) & 3;
            Pex[i] = Pxv[ip] - Pxv[i];
            Pey[i] = Pyv[ip] - Pyv[i];
            Qex[i] = Qxv[ip] - Qxv[i];
            Qey[i] = Qyv[ip] - Qyv[i];
            cP[i]  = Pxv[i] * Pyv[ip] - Pyv[i] * Pxv[ip];
            cQ[i]  = Qxv[i] * Qyv[ip] - Qyv[i] * Qxv[ip];
        }

        // ---- both signed-distance matrices (corner coords die after this) ----
        float dPQ[4][4], dQP[4][4];   // dPQ[i][j]: P vtx i vs Q edge j; dQP[j][i]: Q vtx j vs P edge i
        #pragma unroll
        for (int i = 0; i < 4; i++) {
            #pragma unroll
            for (int j = 0; j < 4; j++) {
                dPQ[i][j] = fmaf(Qex[j], Pyv[i], fmaf(-Qey[j], Pxv[i], cQ[j]));
                dQP[i][j] = fmaf(Pex[j], Qyv[i], fmaf(-Pey[j], Qxv[i], cP[j]));
            }
        }

        // ---- fused clip: one rcp per (i,j) cell serves both passes ----
        float t0P[4], t1P[4], t0Q[4], t1Q[4];
        #pragma unroll
        for (int i = 0; i < 4; i++) { t0P[i] = 0.0f; t1P[i] = 1.0f;
                                      t0Q[i] = 0.0f; t1Q[i] = 1.0f; }
        #pragma unroll
        for (int i = 0; i < 4; i++) {           // P edge i  <-> P plane i
            int ip = (i + 1) & 3;
            #pragma unroll
            for (int j = 0; j < 4; j++) {       // Q plane j <-> Q edge j
                int jp = (j + 1) & 3;
                float dc1 = dPQ[i][j], dd1 = dPQ[ip][j];
                float denom = dc1 - dd1;        // cross(Pe_i, Qe_j)
                float ds = copysignf(fmaxf(fabsf(denom), 1e-12f), denom);
                float r  = __builtin_amdgcn_rcpf(ds);
                bool  e1 = denom < 0.0f;        // pass-1 entering
                // pass 1: P edge i vs Q plane j
                float tt1 = dc1 * r;
                t0P[i] = fmaxf(t0P[i], e1 ? tt1 : 0.0f);
                t1P[i] = fminf(t1P[i], e1 ? 1.0f : tt1);
                // pass 2: Q edge j vs P plane i (denom2 = -denom, enter2 = !e1)
                float tt2 = dQP[j][i] * (-r);
                t0Q[j] = fmaxf(t0Q[j], e1 ? 0.0f : tt2);
                t1Q[j] = fminf(t1Q[j], e1 ? tt2 : 1.0f);
            }
        }

        float area2 = 0.0f;
        #pragma unroll
        for (int i = 0; i < 4; i++) {
            area2 = fmaf(fmaxf(t1P[i], t0P[i]) - t0P[i], cP[i], area2);
            area2 = fmaf(fmaxf(t1Q[i], t0Q[i]) - t0Q[i], cQ[i], area2);
        }
        float inter = 0.5f * fabsf(area2);

        // ---- CIoU loss (rcp-based divides; ~1e-6 rel err, threshold 3.5e-3) ----
        float a1 = pw * ph, a2 = tw * th;
        float iou = fmaxf(inter * __builtin_amdgcn_rcpf(a1 + a2 - inter), EPSF);
        float dx0 = px - tx, dy0 = py - ty;
        float cd = dx0 * dx0 + dy0 * dy0;
        // atan(u)-atan(v) = atan((u-v)/(1+uv)) for u,v>0
        float u  = tw * __builtin_amdgcn_rcpf(th + EPSF);
        float v  = pw * __builtin_amdgcn_rcpf(ph + EPSF);
        float da = fast_atan((u - v) * __builtin_amdgcn_rcpf(fmaf(u, v, 1.0f)));
        const float c4pi2 = 4.0f / (3.14159265358979323846f * 3.14159265358979323846f);
        float aspect = c4pi2 * da * da;
        float onemiou = 1.0f - iou;
        float vterm = aspect * __builtin_amdgcn_rcpf(onemiou + aspect);
        float alpha = vterm  * __builtin_amdgcn_rcpf(onemiou + vterm);
        float loss = onemiou
                   + cd * __builtin_amdgcn_rcpf(fmaf(pw, pw, fmaf(ph, ph, EPSF)))
                   + alpha * vterm;
        contrib = loss * wgt;
    }

    float s = block_reduce_sum<4>(contrib);
    if (threadIdx.x == 0) partial[blockIdx.x] = s;
}

__global__ void __launch_bounds__(1024)
reduce_final_kernel(const float* __restrict__ partial, int nparts, float invN,
                    float* __restrict__ out)
{
    float s = 0.0f;
    for (int i = threadIdx.x; i < nparts; i += 1024) s += partial[i];
    s = block_reduce_sum<16>(s);
    if (threadIdx.x == 0) out[0] = s * invN;
}

extern "C" void kernel_launch(void* const* d_in, const int* in_sizes, int n_in,
                              void* d_out, int out_size, void* d_ws, size_t ws_size,
                              hipStream_t stream) {
    const float* pred   = (const float*)d_in[0];
    const float* target = (const float*)d_in[1];
    const float* weight = (const float*)d_in[2];
    int N = in_sizes[2];              // weight has N elements
    float* partial = (float*)d_ws;    // one float per block, each block writes its own slot

    int blocks = (N + 255) / 256;
    ciou_loss_kernel<<<blocks, 256, 0, stream>>>(pred, target, weight, partial, N);
    reduce_final_kernel<<<1, 1024, 0, stream>>>(partial, blocks, 1.0f / (float)N,
                                                (float*)d_out);
}

// Round 7
// 91.487 us; speedup vs baseline: 4.3721x; 1.0061x over previous
//
#include <hip/hip_runtime.h>
#include <math.h>
#include <string.h>

#define EPSF 1e-6f

// Wave(64)-then-LDS block reduction, templated on wave count. Valid on thread 0.
template <int NWAVES>
__device__ __forceinline__ float block_reduce_sum(float v) {
    #pragma unroll
    for (int off = 32; off > 0; off >>= 1)
        v += __shfl_down(v, off, 64);
    __shared__ float smem[NWAVES];
    int lane = threadIdx.x & 63;
    int wid  = threadIdx.x >> 6;
    if (lane == 0) smem[wid] = v;
    __syncthreads();
    float s = 0.0f;
    if (threadIdx.x == 0) {
        #pragma unroll
        for (int w = 0; w < NWAVES; w++) s += smem[w];
    }
    return s;
}

// atan via degree-11 minimax on [0,1] + reciprocal fold; |err| ~1e-6.
__device__ __forceinline__ float fast_atan(float x) {
    const float a1  =  0.99997726f, a3 = -0.33262347f, a5  =  0.19354346f,
                a7  = -0.11643287f, a9 =  0.05265332f, a11 = -0.01172120f;
    float ax  = fabsf(x);
    bool  big = ax > 1.0f;
    float z   = big ? __builtin_amdgcn_rcpf(ax) : ax;   // z in [0,1]
    float z2  = z * z;
    float p   = fmaf(z2, a11, a9);
    p = fmaf(z2, p, a7);
    p = fmaf(z2, p, a5);
    p = fmaf(z2, p, a3);
    p = fmaf(z2, p, a1);
    float r = z * p;
    r = big ? (1.57079632679f - r) : r;
    return copysignf(r, x);
}

// 16B load from a 4B-aligned address (gfx9+ supports align-4 dwordx4).
__device__ __forceinline__ float4 load4u(const float* p) {
    float4 v;
    __builtin_memcpy(&v, p, 16);
    return v;
}

// 2*Area(P ∩ Q) = Σ_edges (t1 - t0) * cross(v_i, v_{i+1})  [Liang-Barsky t-range
// per edge against the other quad's 4 half-planes]. Branchless, register-only.
//
// Signed distance of X from CCW edge (v -> v'), e = v'-v, c = cross(v, v'):
//   d = e.x*X.y - e.y*X.x + c   (>= 0 inside).
// Shared-denominator identities (verified R6, passed absmax 0):
//   denom = dPQ[i][j] - dPQ[i+1][j] = cross(Pe_i, Qe_j)
//   pass-1 (P edge i vs Q plane j): slope = -denom, enter iff denom<0, t = dPQ[i][j]/denom
//   pass-2 (Q edge j vs P plane i): slope = +denom, enter iff denom>0, t = -dQP[j][i]/denom
// Register schedule: j outer, amortize the 4 P-vertex distances per Q-plane;
// compute the single pass-2 distance per cell on the fly. Peak live ~70 VGPR.
__global__ void __launch_bounds__(256, 5)
ciou_loss_kernel(const float* __restrict__ pred,
                 const float* __restrict__ target,
                 const float* __restrict__ weight,
                 float* __restrict__ partial,
                 int N)
{
    int tid = threadIdx.x;
    int idx = blockIdx.x * 256 + tid;
    float contrib = 0.0f;
    if (idx < N) {
        const float* p = pred   + (size_t)idx * 5;
        const float* t = target + (size_t)idx * 5;
        float4 P4 = load4u(p);   float pa = p[4];
        float4 T4 = load4u(t);   float ta = t[4];
        float wgt = weight[idx];
        float px = P4.x, py = P4.y, pw = P4.z, ph = P4.w;
        float tx = T4.x, ty = T4.y, tw = T4.z, th = T4.w;

        // ---- epilogue scalars up front so box params die early ----
        float dx0 = px - tx, dy0 = py - ty;
        float cd   = dx0 * dx0 + dy0 * dy0;
        float a12  = pw * ph + tw * th;
        float wh2i = __builtin_amdgcn_rcpf(fmaf(pw, pw, fmaf(ph, ph, EPSF)));
        float u  = tw * __builtin_amdgcn_rcpf(th + EPSF);
        float v  = pw * __builtin_amdgcn_rcpf(ph + EPSF);
        float da = fast_atan((u - v) * __builtin_amdgcn_rcpf(fmaf(u, v, 1.0f)));
        const float c4pi2 = 4.0f / (3.14159265358979323846f * 3.14159265358979323846f);
        float aspect = c4pi2 * da * da;

        // Recenter at midpoint of centers: operands O(box size), not O(1024).
        float cx0 = 0.5f * (px + tx), cy0 = 0.5f * (py + ty);

        // ---- corners (CCW): (+,+), (-,+), (-,-), (+,-) ----
        const float sgx[4] = { 0.5f, -0.5f, -0.5f,  0.5f };
        const float sgy[4] = { 0.5f,  0.5f, -0.5f, -0.5f };
        float Pxv[4], Pyv[4], Qxv[4], Qyv[4];
        float ca, sa, cb, sb;
        __sincosf(pa, &sa, &ca);
        __sincosf(ta, &sb, &cb);
        #pragma unroll
        for (int i = 0; i < 4; i++) {
            float x4 = sgx[i] * pw, y4 = sgy[i] * ph;
            Pxv[i] = x4 * ca - y4 * sa + (px - cx0);
            Pyv[i] = x4 * sa + y4 * ca + (py - cy0);
            float u4 = sgx[i] * tw, v4 = sgy[i] * th;
            Qxv[i] = u4 * cb - v4 * sb + (tx - cx0);
            Qyv[i] = u4 * sb + v4 * cb + (ty - cy0);
        }

        // ---- edge vectors + cross constants c[j] = cross(v_j, v_{j+1}) ----
        float Pex[4], Pey[4], Qex[4], Qey[4], cP[4], cQ[4];
        #pragma unroll
        for (int i = 0; i < 4; i++) {
            int ip = (i + 1) & 3;
            Pex[i] = Pxv[ip] - Pxv[i];
            Pey[i] = Pyv[ip] - Pyv[i];
            Qex[i] = Qxv[ip] - Qxv[i];
            Qey[i] = Qyv[ip] - Qyv[i];
            cP[i]  = Pxv[i] * Pyv[ip] - Pyv[i] * Pxv[ip];
            cQ[i]  = Qxv[i] * Qyv[ip] - Qyv[i] * Qxv[ip];
        }

        // ---- fused clip, register-lean schedule ----
        float t0P[4], t1P[4], t0Q[4], t1Q[4];
        #pragma unroll
        for (int i = 0; i < 4; i++) { t0P[i] = 0.0f; t1P[i] = 1.0f;
                                      t0Q[i] = 0.0f; t1Q[i] = 1.0f; }
        #pragma unroll
        for (int j = 0; j < 4; j++) {           // Q plane j / Q edge j
            // distances of the 4 P vertices from Q plane j (reused by 4 cells)
            float d[4];
            #pragma unroll
            for (int i = 0; i < 4; i++)
                d[i] = fmaf(Qex[j], Pyv[i], fmaf(-Qey[j], Pxv[i], cQ[j]));
            #pragma unroll
            for (int i = 0; i < 4; i++) {       // P edge i / P plane i
                int ip = (i + 1) & 3;
                float dc1 = d[i];
                float denom = dc1 - d[ip];      // cross(Pe_i, Qe_j)
                float ds = copysignf(fmaxf(fabsf(denom), 1e-12f), denom);
                float r  = __builtin_amdgcn_rcpf(ds);
                bool  e1 = denom < 0.0f;        // pass-1 entering
                // pass 1: P edge i vs Q plane j
                float tt1 = dc1 * r;
                t0P[i] = fmaxf(t0P[i], e1 ? tt1 : 0.0f);
                t1P[i] = fminf(t1P[i], e1 ? 1.0f : tt1);
                // pass 2: Q edge j vs P plane i (slope=+denom, enter = !e1)
                float dc2 = fmaf(Pex[i], Qyv[j], fmaf(-Pey[i], Qxv[j], cP[i]));
                float tt2 = dc2 * (-r);
                t0Q[j] = fmaxf(t0Q[j], e1 ? 0.0f : tt2);
                t1Q[j] = fminf(t1Q[j], e1 ? tt2 : 1.0f);
            }
        }

        float area2 = 0.0f;
        #pragma unroll
        for (int i = 0; i < 4; i++) {
            area2 = fmaf(fmaxf(t1P[i], t0P[i]) - t0P[i], cP[i], area2);
            area2 = fmaf(fmaxf(t1Q[i], t0Q[i]) - t0Q[i], cQ[i], area2);
        }
        float inter = 0.5f * fabsf(area2);

        // ---- CIoU loss ----
        float iou = fmaxf(inter * __builtin_amdgcn_rcpf(a12 - inter), EPSF);
        float onemiou = 1.0f - iou;
        float vterm = aspect * __builtin_amdgcn_rcpf(onemiou + aspect);
        float alpha = vterm  * __builtin_amdgcn_rcpf(onemiou + vterm);
        float loss = onemiou + cd * wh2i + alpha * vterm;
        contrib = loss * wgt;
    }

    float s = block_reduce_sum<4>(contrib);
    if (threadIdx.x == 0) partial[blockIdx.x] = s;
}

__global__ void __launch_bounds__(1024)
reduce_final_kernel(const float* __restrict__ partial, int nparts, float invN,
                    float* __restrict__ out)
{
    float s = 0.0f;
    for (int i = threadIdx.x; i < nparts; i += 1024) s += partial[i];
    s = block_reduce_sum<16>(s);
    if (threadIdx.x == 0) out[0] = s * invN;
}

extern "C" void kernel_launch(void* const* d_in, const int* in_sizes, int n_in,
                              void* d_out, int out_size, void* d_ws, size_t ws_size,
                              hipStream_t stream) {
    const float* pred   = (const float*)d_in[0];
    const float* target = (const float*)d_in[1];
    const float* weight = (const float*)d_in[2];
    int N = in_sizes[2];              // weight has N elements
    float* partial = (float*)d_ws;    // one float per block, each block writes its own slot

    int blocks = (N + 255) / 256;
    ciou_loss_kernel<<<blocks, 256, 0, stream>>>(pred, target, weight, partial, N);
    reduce_final_kernel<<<1, 1024, 0, stream>>>(partial, blocks, 1.0f / (float)N,
                                                (float*)d_out);
}